// Round 4
// baseline (582.484 us; speedup 1.0000x reference)
//
#include <hip/hip_runtime.h>

#define HIDDEN    128
#define N_NODES_C 50000
#define N_PROP_C  25000
#define N_EDGES_C 600000
#define CAP       64      // fixed bin capacity; in-degree ~ Poisson(24), P(>=64) ~ 1e-10
#define NB_ROWS   1024    // row-work blocks in fused kernel
#define NB_TAIL   512     // tail-copy blocks in fused kernel

// ---- Scatter into fixed-capacity bins (no hist, no scan) ----------------
// pos[dst] must be zeroed before launch; after the kernel it equals the count.
__global__ __launch_bounds__(256) void scatter_kernel(
    const int* __restrict__ ps, const int* __restrict__ pd,
    const int* __restrict__ ss, const int* __restrict__ sd,
    int* __restrict__ posP, int* __restrict__ posS,
    int* __restrict__ binP, int* __restrict__ binS)
{
    int i = blockIdx.x * 256 + threadIdx.x;
    if (i < N_EDGES_C) {
        int d = pd[i];
        int r = atomicAdd(&posP[d], 1);
        if (r < CAP) binP[d * CAP + r] = ps[i];
    } else if (i < 2 * N_EDGES_C) {
        int j = i - N_EDGES_C;
        int d = sd[j];
        int r = atomicAdd(&posS[d], 1);
        if (r < CAP) binS[d * CAP + r] = ss[j];
    }
}

// ---- Fused: pull both aggregations + GEMV + relu + adds + tail copy -----
// Blocks [0,NB_ROWS): 8 rows per iteration (32 lanes x float4 per row).
// Blocks [NB_ROWS, NB_ROWS+NB_TAIL): stream rows [N_PROP, N_NODES) to out.
__global__ __launch_bounds__(256) void fused_kernel(
    const float* __restrict__ prop_z, const float* __restrict__ mol_z,
    const int* __restrict__ binP, const int* __restrict__ cntP,
    const int* __restrict__ binS, const int* __restrict__ cntS,
    const float* __restrict__ W, const float* __restrict__ bias,
    float* __restrict__ out)
{
    if (blockIdx.x >= NB_ROWS) {
        const float4* src = (const float4*)(prop_z + (size_t)N_PROP_C * HIDDEN);
        float4*       dst = (float4*)(out + (size_t)N_PROP_C * HIDDEN);
        const int n4 = (N_NODES_C - N_PROP_C) * HIDDEN / 4;   // 800000
        for (int i = (blockIdx.x - NB_ROWS) * 256 + threadIdx.x; i < n4;
             i += NB_TAIL * 256)
            dst[i] = src[i];
        return;
    }

    // W staged as float4 per (row c, slot): slot = k4 ^ (c&31)  -> b128 reads
    // in the k-loop hit a permutation of contiguous slots = conflict-free.
    __shared__ float4 Wl[HIDDEN * 32];        // 64 KB
    __shared__ float  rowP[8][HIDDEN];        // 4 KB
    __shared__ float  rowS[8][HIDDEN];        // 4 KB

    const float4* W4 = (const float4*)W;
    for (int i = threadIdx.x; i < HIDDEN * 32; i += 256) {
        int c = i >> 5, k4 = i & 31;
        Wl[(c << 5) | (k4 ^ (c & 31))] = W4[i];
    }
    const int g    = threadIdx.x >> 5;        // row slot 0..7 (gather phase)
    const int lane = threadIdx.x & 31;
    const int c    = threadIdx.x & 127;       // output channel (GEMV phase)
    const int half = threadIdx.x >> 7;        // row group 0..1 (GEMV phase)
    const float bc = bias[c];
    __syncthreads();

    for (int base = blockIdx.x * 8; base < N_PROP_C; base += NB_ROWS * 8) {
        int r = base + g;
        float4 accP = make_float4(0.f, 0.f, 0.f, 0.f);
        float4 accS = make_float4(0.f, 0.f, 0.f, 0.f);
        if (r < N_PROP_C) {
            // parent gather (prop_z)
            {
                const float4* tab = (const float4*)prop_z;
                const int* bin = binP + r * CAP;
                int n = min(cntP[r], CAP);
                int i = 0;
                for (; i + 4 <= n; i += 4) {
                    int s0 = bin[i], s1 = bin[i+1], s2 = bin[i+2], s3 = bin[i+3];
                    float4 a = tab[s0 * 32 + lane];
                    float4 b = tab[s1 * 32 + lane];
                    float4 e = tab[s2 * 32 + lane];
                    float4 d = tab[s3 * 32 + lane];
                    accP.x += (a.x + b.x) + (e.x + d.x);
                    accP.y += (a.y + b.y) + (e.y + d.y);
                    accP.z += (a.z + b.z) + (e.z + d.z);
                    accP.w += (a.w + b.w) + (e.w + d.w);
                }
                for (; i < n; ++i) {
                    float4 a = tab[bin[i] * 32 + lane];
                    accP.x += a.x; accP.y += a.y; accP.z += a.z; accP.w += a.w;
                }
            }
            // sibling gather (mol_z)
            {
                const float4* tab = (const float4*)mol_z;
                const int* bin = binS + r * CAP;
                int n = min(cntS[r], CAP);
                int i = 0;
                for (; i + 4 <= n; i += 4) {
                    int s0 = bin[i], s1 = bin[i+1], s2 = bin[i+2], s3 = bin[i+3];
                    float4 a = tab[s0 * 32 + lane];
                    float4 b = tab[s1 * 32 + lane];
                    float4 e = tab[s2 * 32 + lane];
                    float4 d = tab[s3 * 32 + lane];
                    accS.x += (a.x + b.x) + (e.x + d.x);
                    accS.y += (a.y + b.y) + (e.y + d.y);
                    accS.z += (a.z + b.z) + (e.z + d.z);
                    accS.w += (a.w + b.w) + (e.w + d.w);
                }
                for (; i < n; ++i) {
                    float4 a = tab[bin[i] * 32 + lane];
                    accS.x += a.x; accS.y += a.y; accS.z += a.z; accS.w += a.w;
                }
            }
        }
        ((float4*)rowP[g])[lane] = accP;
        ((float4*)rowS[g])[lane] = accS;
        __syncthreads();

        // GEMV: each half computes 4 rows; one Wl read serves 4 FMAs x 4 ch.
        const int r0 = half * 4;
        float a0 = bc, a1 = bc, a2 = bc, a3 = bc;
        #pragma unroll
        for (int k4 = 0; k4 < 32; ++k4) {
            float4 w  = Wl[(c << 5) | (k4 ^ (c & 31))];
            float4 p0 = ((const float4*)rowP[r0 + 0])[k4];
            float4 p1 = ((const float4*)rowP[r0 + 1])[k4];
            float4 p2 = ((const float4*)rowP[r0 + 2])[k4];
            float4 p3 = ((const float4*)rowP[r0 + 3])[k4];
            a0 = fmaf(w.x, p0.x, fmaf(w.y, p0.y, fmaf(w.z, p0.z, fmaf(w.w, p0.w, a0))));
            a1 = fmaf(w.x, p1.x, fmaf(w.y, p1.y, fmaf(w.z, p1.z, fmaf(w.w, p1.w, a1))));
            a2 = fmaf(w.x, p2.x, fmaf(w.y, p2.y, fmaf(w.z, p2.z, fmaf(w.w, p2.w, a2))));
            a3 = fmaf(w.x, p3.x, fmaf(w.y, p3.y, fmaf(w.z, p3.z, fmaf(w.w, p3.w, a3))));
        }
        float acc[4] = {a0, a1, a2, a3};
        #pragma unroll
        for (int j = 0; j < 4; ++j) {
            int row = base + r0 + j;
            if (row < N_PROP_C) {
                float u = fmaxf(acc[j], 0.0f);
                out[(size_t)row * HIDDEN + c] =
                    prop_z[(size_t)row * HIDDEN + c] + u + rowS[r0 + j][c];
            }
        }
        __syncthreads();
    }
}

extern "C" void kernel_launch(void* const* d_in, const int* in_sizes, int n_in,
                              void* d_out, int out_size, void* d_ws, size_t ws_size,
                              hipStream_t stream)
{
    const float* prop_z      = (const float*)d_in[0];
    const float* mol_z       = (const float*)d_in[1];
    const float* W           = (const float*)d_in[2];
    const float* b           = (const float*)d_in[3];
    const int*   parent_src  = (const int*)d_in[4];
    const int*   parent_dst  = (const int*)d_in[5];
    const int*   sibling_src = (const int*)d_in[6];
    const int*   sibling_dst = (const int*)d_in[7];

    float* out = (float*)d_out;

    // ws layout: bins (uninitialized ok) + pos/count arrays (zeroed)
    int* binP = (int*)d_ws;                          // 25000*64 = 6.4 MB
    int* binS = binP + (size_t)N_PROP_C * CAP;       // 6.4 MB
    int* posP = binS + (size_t)N_PROP_C * CAP;       // 100 KB
    int* posS = posP + N_PROP_C;                     // 100 KB

    hipMemsetAsync(posP, 0, 2 * N_PROP_C * sizeof(int), stream);

    int blocks_2e = (2 * N_EDGES_C + 255) / 256;
    scatter_kernel<<<blocks_2e, 256, 0, stream>>>(parent_src, parent_dst,
                                                  sibling_src, sibling_dst,
                                                  posP, posS, binP, binS);

    fused_kernel<<<NB_ROWS + NB_TAIL, 256, 0, stream>>>(
        prop_z, mol_z, binP, posP, binS, posS, W, b, out);
}

// Round 5
// 284.934 us; speedup vs baseline: 2.0443x; 2.0443x over previous
//
#include <hip/hip_runtime.h>

#define HIDDEN    128
#define N_NODES_C 50000
#define N_PROP_C  25000
#define N_EDGES_C 600000
#define CAP       64       // in-degree ~ Poisson(24); P(>=64) ~ 1e-10 per bin
#define PULL_BLOCKS 6250   // 50000 gather tasks, 8 per block
#define TAIL_BLOCKS 512
#define GEMV_BLOCKS 1024

// ---- Scatter into fixed-capacity bins (no hist, no scan) ----------------
__global__ __launch_bounds__(256) void scatter_kernel(
    const int* __restrict__ ps, const int* __restrict__ pd,
    const int* __restrict__ ss, const int* __restrict__ sd,
    int* __restrict__ posP, int* __restrict__ posS,
    int* __restrict__ binP, int* __restrict__ binS)
{
    int i = blockIdx.x * 256 + threadIdx.x;
    if (i < N_EDGES_C) {
        int d = pd[i];
        int r = atomicAdd(&posP[d], 1);
        if (r < CAP) binP[d * CAP + r] = ps[i];
    } else if (i < 2 * N_EDGES_C) {
        int j = i - N_EDGES_C;
        int d = sd[j];
        int r = atomicAdd(&posS[d], 1);
        if (r < CAP) binS[d * CAP + r] = ss[j];
    }
}

// ---- Lean pull (no LDS, register accumulate) + fused tail copy ----------
// task < N_PROP: parent row (gather prop_z -> aggP); else sibling (mol_z -> aggS).
// 32 lanes per row, one float4 per lane. Blocks >= PULL_BLOCKS stream the tail.
__global__ __launch_bounds__(256) void pull_tail_kernel(
    const float* __restrict__ prop_z, const float* __restrict__ mol_z,
    const int* __restrict__ binP, const int* __restrict__ cntP,
    const int* __restrict__ binS, const int* __restrict__ cntS,
    float* __restrict__ aggP, float* __restrict__ aggS,
    float* __restrict__ out)
{
    if (blockIdx.x >= PULL_BLOCKS) {
        const float4* src = (const float4*)(prop_z + (size_t)N_PROP_C * HIDDEN);
        float4*       dst = (float4*)(out + (size_t)N_PROP_C * HIDDEN);
        const int n4 = (N_NODES_C - N_PROP_C) * HIDDEN / 4;   // 800000
        for (int i = (blockIdx.x - PULL_BLOCKS) * 256 + threadIdx.x; i < n4;
             i += TAIL_BLOCKS * 256)
            dst[i] = src[i];
        return;
    }
    int task = blockIdx.x * 8 + (threadIdx.x >> 5);
    int lane = threadIdx.x & 31;
    const float4* tab; const int* bin; float4* dst; int r, n;
    if (task < N_PROP_C) {
        r = task;            tab = (const float4*)prop_z;
        bin = binP + r * CAP; n = min(cntP[r], CAP); dst = (float4*)aggP;
    } else {
        r = task - N_PROP_C; tab = (const float4*)mol_z;
        bin = binS + r * CAP; n = min(cntS[r], CAP); dst = (float4*)aggS;
    }
    float4 acc = make_float4(0.f, 0.f, 0.f, 0.f);
    int i = 0;
    for (; i + 4 <= n; i += 4) {                 // 4 independent gathers in flight
        int s0 = bin[i], s1 = bin[i + 1], s2 = bin[i + 2], s3 = bin[i + 3];
        float4 a = tab[s0 * 32 + lane];
        float4 b = tab[s1 * 32 + lane];
        float4 c = tab[s2 * 32 + lane];
        float4 d = tab[s3 * 32 + lane];
        acc.x += (a.x + b.x) + (c.x + d.x);
        acc.y += (a.y + b.y) + (c.y + d.y);
        acc.z += (a.z + b.z) + (c.z + d.z);
        acc.w += (a.w + b.w) + (c.w + d.w);
    }
    for (; i < n; ++i) {
        float4 a = tab[bin[i] * 32 + lane];
        acc.x += a.x; acc.y += a.y; acc.z += a.z; acc.w += a.w;
    }
    dst[r * 32 + lane] = acc;
}

// ---- GEMV + epilogue: out[r] = prop_z[r] + relu(aggP[r]@W^T + b) + aggS[r]
// W staged swizzled: slot = k4 ^ (c&31) -> k-loop b128 reads are conflict-free.
// One W read serves 4 rows x 4 channels; row reads are LDS broadcasts.
__global__ __launch_bounds__(256) void gemv_out_kernel(
    const float* __restrict__ prop_z,
    const float* __restrict__ aggP, const float* __restrict__ aggS,
    const float* __restrict__ W, const float* __restrict__ bias,
    float* __restrict__ out)
{
    __shared__ float4 Wl[HIDDEN * 32];        // 64 KB
    __shared__ float  rowP[8][HIDDEN];        // 4 KB
    __shared__ float  rowS[8][HIDDEN];        // 4 KB

    const float4* W4 = (const float4*)W;
    for (int i = threadIdx.x; i < HIDDEN * 32; i += 256) {
        int c = i >> 5, k4 = i & 31;
        Wl[(c << 5) | (k4 ^ (c & 31))] = W4[i];
    }
    const int t    = threadIdx.x;
    const int g    = t >> 5;                  // staging row 0..7
    const int l4   = t & 31;                  // staging float4 slot
    const int c    = t & 127;                 // output channel
    const int half = t >> 7;                  // row group 0..1
    const float bc = bias[c];
    __syncthreads();

    // N_PROP_C % 8 == 0 -> no bounds checks needed inside.
    for (int base = blockIdx.x * 8; base < N_PROP_C; base += GEMV_BLOCKS * 8) {
        ((float4*)rowP[g])[l4] = ((const float4*)aggP)[(base + g) * 32 + l4];
        ((float4*)rowS[g])[l4] = ((const float4*)aggS)[(base + g) * 32 + l4];
        __syncthreads();

        const int r0 = half * 4;
        float a0 = bc, a1 = bc, a2 = bc, a3 = bc;
        #pragma unroll
        for (int k4i = 0; k4i < 32; ++k4i) {
            float4 w  = Wl[(c << 5) | (k4i ^ (c & 31))];
            float4 p0 = ((const float4*)rowP[r0 + 0])[k4i];   // broadcast
            float4 p1 = ((const float4*)rowP[r0 + 1])[k4i];
            float4 p2 = ((const float4*)rowP[r0 + 2])[k4i];
            float4 p3 = ((const float4*)rowP[r0 + 3])[k4i];
            a0 = fmaf(w.x, p0.x, fmaf(w.y, p0.y, fmaf(w.z, p0.z, fmaf(w.w, p0.w, a0))));
            a1 = fmaf(w.x, p1.x, fmaf(w.y, p1.y, fmaf(w.z, p1.z, fmaf(w.w, p1.w, a1))));
            a2 = fmaf(w.x, p2.x, fmaf(w.y, p2.y, fmaf(w.z, p2.z, fmaf(w.w, p2.w, a2))));
            a3 = fmaf(w.x, p3.x, fmaf(w.y, p3.y, fmaf(w.z, p3.z, fmaf(w.w, p3.w, a3))));
        }
        float acc[4] = {a0, a1, a2, a3};
        #pragma unroll
        for (int j = 0; j < 4; ++j) {
            int row = base + r0 + j;
            out[(size_t)row * HIDDEN + c] =
                prop_z[(size_t)row * HIDDEN + c] + fmaxf(acc[j], 0.0f)
                + rowS[r0 + j][c];
        }
        __syncthreads();
    }
}

extern "C" void kernel_launch(void* const* d_in, const int* in_sizes, int n_in,
                              void* d_out, int out_size, void* d_ws, size_t ws_size,
                              hipStream_t stream)
{
    const float* prop_z      = (const float*)d_in[0];
    const float* mol_z       = (const float*)d_in[1];
    const float* W           = (const float*)d_in[2];
    const float* b           = (const float*)d_in[3];
    const int*   parent_src  = (const int*)d_in[4];
    const int*   parent_dst  = (const int*)d_in[5];
    const int*   sibling_src = (const int*)d_in[6];
    const int*   sibling_dst = (const int*)d_in[7];

    float* out = (float*)d_out;

    // ws layout
    int*   binP = (int*)d_ws;                                   // 6.4 MB
    int*   binS = binP + (size_t)N_PROP_C * CAP;                // 6.4 MB
    int*   posP = binS + (size_t)N_PROP_C * CAP;                // 100 KB
    int*   posS = posP + N_PROP_C;                              // 100 KB
    float* aggP = (float*)(posS + N_PROP_C);                    // 12.8 MB
    float* aggS = aggP + (size_t)N_PROP_C * HIDDEN;             // 12.8 MB

    hipMemsetAsync(posP, 0, 2 * N_PROP_C * sizeof(int), stream);

    int blocks_2e = (2 * N_EDGES_C + 255) / 256;
    scatter_kernel<<<blocks_2e, 256, 0, stream>>>(parent_src, parent_dst,
                                                  sibling_src, sibling_dst,
                                                  posP, posS, binP, binS);

    pull_tail_kernel<<<PULL_BLOCKS + TAIL_BLOCKS, 256, 0, stream>>>(
        prop_z, mol_z, binP, posP, binS, posS, aggP, aggS, out);

    gemv_out_kernel<<<GEMV_BLOCKS, 256, 0, stream>>>(
        prop_z, aggP, aggS, W, b, out);
}

// Round 6
// 261.674 us; speedup vs baseline: 2.2260x; 1.0889x over previous
//
#include <hip/hip_runtime.h>

#define HIDDEN    128
#define N_NODES_C 50000
#define N_PROP_C  25000
#define N_EDGES_C 600000
#define CAP       64       // in-degree ~ Poisson(24); P(>=64) ~ 1e-10 per bin
#define PULL_BLOCKS 6250   // 50000 gather tasks, 8 per block
#define TAIL_BLOCKS 512
#define MFMA_BLOCKS 391    // ceil(25000/16 rows-per-wave / 4 waves-per-block)

typedef __attribute__((ext_vector_type(8))) short short8;   // 8 x bf16 (4 VGPR)
typedef __attribute__((ext_vector_type(4))) float f32x4;    // mfma C/D

__device__ __forceinline__ unsigned short f2bf(float x) {   // fp32 -> bf16 RNE
    unsigned u = __float_as_uint(x);
    u += 0x7fffu + ((u >> 16) & 1u);
    return (unsigned short)(u >> 16);
}

// ---- Scatter into fixed-capacity bins (no hist, no scan) ----------------
__global__ __launch_bounds__(256) void scatter_kernel(
    const int* __restrict__ ps, const int* __restrict__ pd,
    const int* __restrict__ ss, const int* __restrict__ sd,
    int* __restrict__ posP, int* __restrict__ posS,
    int* __restrict__ binP, int* __restrict__ binS)
{
    int i = blockIdx.x * 256 + threadIdx.x;
    if (i < N_EDGES_C) {
        int d = pd[i];
        int r = atomicAdd(&posP[d], 1);
        if (r < CAP) binP[d * CAP + r] = ps[i];
    } else if (i < 2 * N_EDGES_C) {
        int j = i - N_EDGES_C;
        int d = sd[j];
        int r = atomicAdd(&posS[d], 1);
        if (r < CAP) binS[d * CAP + r] = ss[j];
    }
}

// ---- Lean pull, 8 gathers in flight; parent rows stored bf16 ------------
// task < N_PROP: gather prop_z -> aggPb (bf16); else mol_z -> aggS (fp32).
// 32 lanes per row, 4 channels per lane. Blocks >= PULL_BLOCKS stream tail.
__global__ __launch_bounds__(256) void pull_tail_kernel(
    const float* __restrict__ prop_z, const float* __restrict__ mol_z,
    const int* __restrict__ binP, const int* __restrict__ cntP,
    const int* __restrict__ binS, const int* __restrict__ cntS,
    short* __restrict__ aggPb, float* __restrict__ aggS,
    float* __restrict__ out)
{
    if (blockIdx.x >= PULL_BLOCKS) {
        const float4* src = (const float4*)(prop_z + (size_t)N_PROP_C * HIDDEN);
        float4*       dst = (float4*)(out + (size_t)N_PROP_C * HIDDEN);
        const int n4 = (N_NODES_C - N_PROP_C) * HIDDEN / 4;   // 800000
        for (int i = (blockIdx.x - PULL_BLOCKS) * 256 + threadIdx.x; i < n4;
             i += TAIL_BLOCKS * 256)
            dst[i] = src[i];
        return;
    }
    int task = blockIdx.x * 8 + (threadIdx.x >> 5);
    int lane = threadIdx.x & 31;
    const float4* tab; const int* bin; int r, n;
    bool parent = task < N_PROP_C;
    if (parent) {
        r = task;            tab = (const float4*)prop_z;
        bin = binP + r * CAP; n = min(cntP[r], CAP);
    } else {
        r = task - N_PROP_C; tab = (const float4*)mol_z;
        bin = binS + r * CAP; n = min(cntS[r], CAP);
    }
    float4 acc = make_float4(0.f, 0.f, 0.f, 0.f);
    int i = 0;
    for (; i + 8 <= n; i += 8) {                 // 8 independent gathers in flight
        int s0 = bin[i],     s1 = bin[i + 1], s2 = bin[i + 2], s3 = bin[i + 3];
        int s4 = bin[i + 4], s5 = bin[i + 5], s6 = bin[i + 6], s7 = bin[i + 7];
        float4 a = tab[s0 * 32 + lane];
        float4 b = tab[s1 * 32 + lane];
        float4 c = tab[s2 * 32 + lane];
        float4 d = tab[s3 * 32 + lane];
        float4 e = tab[s4 * 32 + lane];
        float4 f = tab[s5 * 32 + lane];
        float4 g = tab[s6 * 32 + lane];
        float4 h = tab[s7 * 32 + lane];
        acc.x += ((a.x + b.x) + (c.x + d.x)) + ((e.x + f.x) + (g.x + h.x));
        acc.y += ((a.y + b.y) + (c.y + d.y)) + ((e.y + f.y) + (g.y + h.y));
        acc.z += ((a.z + b.z) + (c.z + d.z)) + ((e.z + f.z) + (g.z + h.z));
        acc.w += ((a.w + b.w) + (c.w + d.w)) + ((e.w + f.w) + (g.w + h.w));
    }
    for (; i + 4 <= n; i += 4) {
        int s0 = bin[i], s1 = bin[i + 1], s2 = bin[i + 2], s3 = bin[i + 3];
        float4 a = tab[s0 * 32 + lane];
        float4 b = tab[s1 * 32 + lane];
        float4 c = tab[s2 * 32 + lane];
        float4 d = tab[s3 * 32 + lane];
        acc.x += (a.x + b.x) + (c.x + d.x);
        acc.y += (a.y + b.y) + (c.y + d.y);
        acc.z += (a.z + b.z) + (c.z + d.z);
        acc.w += (a.w + b.w) + (c.w + d.w);
    }
    for (; i < n; ++i) {
        float4 a = tab[bin[i] * 32 + lane];
        acc.x += a.x; acc.y += a.y; acc.z += a.z; acc.w += a.w;
    }
    if (parent) {
        ushort4 p;
        p.x = f2bf(acc.x); p.y = f2bf(acc.y); p.z = f2bf(acc.z); p.w = f2bf(acc.w);
        *(ushort4*)(aggPb + (size_t)r * HIDDEN + lane * 4) = p;
    } else {
        ((float4*)aggS)[r * 32 + lane] = acc;
    }
}

// ---- MFMA epilogue: out[r] = prop_z[r] + relu(aggPb[r]@W^T + b) + aggS[r]
// One wave per 16 rows x 128 cols: 4 A-loads (bf16 direct), 32 swizzled
// ds_read_b128 B-frags, 32 mfma_f32_16x16x32_bf16.
// A layout: row=lane&15, k=(lane>>4)*8+j. B: col=lane&15, same k.
// D layout (m89-verified): col=lane&15, row=(lane>>4)*4+reg.
__global__ __launch_bounds__(256) void mfma_out_kernel(
    const float* __restrict__ prop_z,
    const short* __restrict__ aggPb, const float* __restrict__ aggS,
    const float* __restrict__ W, const float* __restrict__ bias,
    float* __restrict__ out)
{
    __shared__ __align__(16) short Wb[HIDDEN * HIDDEN];   // 32 KB bf16, swizzled

    // Stage W as bf16, 16B chunks XOR-swizzled: chunk' = kb ^ (c&15)
    // -> B-frag reads across 16 cols hit 16 distinct chunks (conflict-free).
    const float4* W4 = (const float4*)W;
    for (int ch = threadIdx.x; ch < HIDDEN * HIDDEN / 8; ch += 256) {
        int c = ch >> 4, kb = ch & 15;
        float4 w0 = W4[ch * 2], w1 = W4[ch * 2 + 1];
        short8 s;
        s[0] = (short)f2bf(w0.x); s[1] = (short)f2bf(w0.y);
        s[2] = (short)f2bf(w0.z); s[3] = (short)f2bf(w0.w);
        s[4] = (short)f2bf(w1.x); s[5] = (short)f2bf(w1.y);
        s[6] = (short)f2bf(w1.z); s[7] = (short)f2bf(w1.w);
        ((short8*)Wb)[c * 16 + (kb ^ (c & 15))] = s;
    }
    __syncthreads();

    int task = blockIdx.x * 4 + (threadIdx.x >> 6);
    int r0 = task * 16;
    if (r0 >= N_PROP_C) return;
    int lane = threadIdx.x & 63;
    int arow = r0 + (lane & 15);
    int aoff = (lane >> 4) * 8;

    f32x4 acc[8] = {};
    #pragma unroll
    for (int ks = 0; ks < 4; ++ks) {
        int k0 = ks * 32 + aoff;
        short8 a = {};
        if (arow < N_PROP_C)
            a = *(const short8*)(aggPb + (size_t)arow * HIDDEN + k0);
        int kb = ks * 4 + (lane >> 4);
        #pragma unroll
        for (int ct = 0; ct < 8; ++ct) {
            int c = ct * 16 + (lane & 15);
            short8 b = ((const short8*)Wb)[c * 16 + (kb ^ (c & 15))];
            acc[ct] = __builtin_amdgcn_mfma_f32_16x16x32_bf16(a, b, acc[ct], 0, 0, 0);
        }
    }

    int rl = (lane >> 4) * 4;
    #pragma unroll
    for (int ct = 0; ct < 8; ++ct) {
        int col = ct * 16 + (lane & 15);
        float bc = bias[col];
        #pragma unroll
        for (int r = 0; r < 4; ++r) {
            int row = r0 + rl + r;
            if (row < N_PROP_C) {
                size_t idx = (size_t)row * HIDDEN + col;
                out[idx] = prop_z[idx] + fmaxf(acc[ct][r] + bc, 0.0f) + aggS[idx];
            }
        }
    }
}

extern "C" void kernel_launch(void* const* d_in, const int* in_sizes, int n_in,
                              void* d_out, int out_size, void* d_ws, size_t ws_size,
                              hipStream_t stream)
{
    const float* prop_z      = (const float*)d_in[0];
    const float* mol_z       = (const float*)d_in[1];
    const float* W           = (const float*)d_in[2];
    const float* b           = (const float*)d_in[3];
    const int*   parent_src  = (const int*)d_in[4];
    const int*   parent_dst  = (const int*)d_in[5];
    const int*   sibling_src = (const int*)d_in[6];
    const int*   sibling_dst = (const int*)d_in[7];

    float* out = (float*)d_out;

    // ws layout (offsets keep 16B alignment for aggPb/aggS)
    int*   binP  = (int*)d_ws;                                  // 6.4 MB
    int*   binS  = binP + (size_t)N_PROP_C * CAP;               // 6.4 MB
    int*   posP  = binS + (size_t)N_PROP_C * CAP;               // 100 KB
    int*   posS  = posP + N_PROP_C;                             // 100 KB
    short* aggPb = (short*)(posS + N_PROP_C);                   // 6.4 MB (bf16)
    float* aggS  = (float*)(aggPb + (size_t)N_PROP_C * HIDDEN); // 12.8 MB

    hipMemsetAsync(posP, 0, 2 * N_PROP_C * sizeof(int), stream);

    int blocks_2e = (2 * N_EDGES_C + 255) / 256;
    scatter_kernel<<<blocks_2e, 256, 0, stream>>>(parent_src, parent_dst,
                                                  sibling_src, sibling_dst,
                                                  posP, posS, binP, binS);

    pull_tail_kernel<<<PULL_BLOCKS + TAIL_BLOCKS, 256, 0, stream>>>(
        prop_z, mol_z, binP, posP, binS, posS, aggPb, aggS, out);

    mfma_out_kernel<<<MFMA_BLOCKS, 256, 0, stream>>>(
        prop_z, aggPb, aggS, W, b, out);
}